// Round 9
// baseline (222.623 us; speedup 1.0000x reference)
//
#include <hip/hip_runtime.h>
#include <hip/hip_bf16.h>
#include <stdint.h>

// Problem: B=2, S=4096, D=512, H=8, hd=64. fp32 in/out, bf16 MFMA internally.
// Dispatches: cvt_all -> gemm_qkv -> flash(split-KV) -> merge_po -> gemm_out.
// R16 = R15/v11 resubmitted verbatim (R15 bench died with an infra-level
// "container failed twice", no counters; R4->R5 precedent says resubmit).
// v11: flash is LDS-throughput-bound (R7 post-mortem). Halve LDS reads per
// FLOP: 64 q-rows/wave (qg 0,1) so each K/V ds_read_b128 feeds 4 MFMAs,
// while split-KV keeps 2 waves/SIMD: 128-thr blocks, grid (32,16,2) = 1024
// blocks = 4/CU. Per-CU staging unchanged. ones-MFMA row-sum replaced by
// VALU f32 sums (+1 scalar permlane swap). sc single-buffered.
//
// ws layout (regions reused across phases):
//   [0,   8MB)  Xb    bf16 [8192,512]     (cvt/gemm_qkv) -> O2 partial (flash)
//   [8,  10MB)  Wqt/Wkt/Wvt/Wot bf16 [512,512] each
//   [10, 18MB)  Qb    bf16 [B,H,S,64]     (flash)        -> Am merged (merge/gemm_out)
//   [18, 26MB)  Kb    bf16 [B,H,S,64]
//   [26, 34MB)  Vtb   bf16 [B,H,64,S]
//   [34, 42MB)  O1 partial bf16 [B,S,512]
//   d_out head (512KB): L row-sums f32 [2][16][4096] (scratch until gemm_out)

typedef __bf16 bf16x8 __attribute__((ext_vector_type(8)));
typedef float f32x4 __attribute__((ext_vector_type(4)));
typedef float f32x16 __attribute__((ext_vector_type(16)));

using as1_void = __attribute__((address_space(1))) void;
using as3_void = __attribute__((address_space(3))) void;

__device__ __forceinline__ void gload16(const void* g, void* l) {
    __builtin_amdgcn_global_load_lds((const as1_void*)g, (as3_void*)l, 16, 0, 0);
}

__device__ __forceinline__ f32x4 mfma16(bf16x8 a, bf16x8 b, f32x4 c) {
    return __builtin_amdgcn_mfma_f32_16x16x32_bf16(a, b, c, 0, 0, 0);
}

__device__ __forceinline__ f32x16 mfma32(bf16x8 a, bf16x8 b, f32x16 c) {
    return __builtin_amdgcn_mfma_f32_32x32x16_bf16(a, b, c, 0, 0, 0);
}

__device__ __forceinline__ uint32_t pkbf(float a, float b) {
    union { __hip_bfloat16 h[2]; uint32_t u; } r;
    r.h[0] = __float2bfloat16(a);   // low 16 = even element
    r.h[1] = __float2bfloat16(b);
    return r.u;
}

// Exchange: a's hi-32-lane values <-> b's lo-32-lane values.
__device__ __forceinline__ void pl32swap(uint32_t& a, uint32_t& b) {
#if __has_builtin(__builtin_amdgcn_permlane32_swap)
    typedef unsigned int uint32x2_t __attribute__((ext_vector_type(2)));
    uint32x2_t r = __builtin_amdgcn_permlane32_swap(a, b, false, false);
    a = r[0];
    b = r[1];
#else
    asm volatile("v_permlane32_swap_b32 %0, %1" : "+v"(a), "+v"(b));
#endif
}

// ---------------------------------------------------------------- converts (fused)
__global__ void cvt_all(const float* __restrict__ X, __hip_bfloat16* __restrict__ Xb,
                        const float* __restrict__ w0, const float* __restrict__ w1,
                        const float* __restrict__ w2, const float* __restrict__ w3,
                        __hip_bfloat16* __restrict__ o0, __hip_bfloat16* __restrict__ o1,
                        __hip_bfloat16* __restrict__ o2, __hip_bfloat16* __restrict__ o3) {
    __shared__ float t[32][33];
    const int bid = blockIdx.x, tid = threadIdx.x;
    if (bid < 1024) {
        const float* W; __hip_bfloat16* O;
        switch (bid >> 8) {
            case 0: W = w0; O = o0; break;
            case 1: W = w1; O = o1; break;
            case 2: W = w2; O = o2; break;
            default: W = w3; O = o3; break;
        }
        int rem = bid & 255;
        int n0 = (rem & 15) * 32, k0 = (rem >> 4) * 32;
        int tx = tid & 31, ty = tid >> 5;
        for (int j = 0; j < 4; ++j)
            t[ty + 8 * j][tx] = W[(size_t)(k0 + ty + 8 * j) * 512 + n0 + tx];
        __syncthreads();
        for (int j = 0; j < 4; ++j)
            O[(size_t)(n0 + ty + 8 * j) * 512 + k0 + tx] = __float2bfloat16(t[tx][ty + 8 * j]);
    } else {
        int i = ((bid - 1024) * 256 + tid) * 4;   // covers exactly 8192*512
        float4 v = *reinterpret_cast<const float4*>(X + i);
        uint2 u;
        u.x = pkbf(v.x, v.y);
        u.y = pkbf(v.z, v.w);
        *reinterpret_cast<uint2*>(Xb + i) = u;
    }
}

// ---------------------------------------------------------------- fused QKV GEMM (R6)
__global__ __launch_bounds__(256, 2) void gemm_qkv(
    const __hip_bfloat16* __restrict__ A, const __hip_bfloat16* __restrict__ Bt,
    const float* __restrict__ bq, const float* __restrict__ bk, const float* __restrict__ bv,
    __hip_bfloat16* __restrict__ Qb, __hip_bfloat16* __restrict__ Kb,
    __hip_bfloat16* __restrict__ Vtb, float qs)
{
    const int K = 512;
    __shared__ __hip_bfloat16 Abuf[128 * 32];
    __shared__ __hip_bfloat16 Bbuf[128 * 32];
    const int tid = threadIdx.x, w = tid >> 6, lane = tid & 63;
    const int col = lane & 15, quad = lane >> 4;
    const int wr = w >> 1, wc = w & 1;
    const int tileN = blockIdx.x * 128, tileM = blockIdx.y * 128;

    f32x4 acc[4][4] = {};

    for (int k0 = 0; k0 < K; k0 += 32) {
        for (int i = 0; i < 2; ++i) {
            int g = w * 2 + i;
            int chunk = g * 64 + lane;
            int row = chunk >> 2, c8 = chunk & 3;
            gload16(A + (size_t)(tileM + row) * K + k0 + c8 * 8, Abuf + g * 512);
            gload16(Bt + (size_t)(tileN + row) * K + k0 + c8 * 8, Bbuf + g * 512);
        }
        __syncthreads();
        bf16x8 af[4], bfr[4];
        for (int mt = 0; mt < 4; ++mt)
            af[mt] = *reinterpret_cast<const bf16x8*>(Abuf + (wr * 64 + mt * 16 + col) * 32 + quad * 8);
        for (int nt = 0; nt < 4; ++nt)
            bfr[nt] = *reinterpret_cast<const bf16x8*>(Bbuf + (wc * 64 + nt * 16 + col) * 32 + quad * 8);
        for (int mt = 0; mt < 4; ++mt)
            for (int nt = 0; nt < 4; ++nt)
                acc[mt][nt] = mfma16(af[mt], bfr[nt], acc[mt][nt]);
        __syncthreads();
    }

    const int seg = (tileN + wc * 64) >> 9;   // wave-uniform
    const float* bias = (seg == 0) ? bq : (seg == 1) ? bk : bv;
    const float scale = (seg == 0) ? qs : 1.0f;
    __hip_bfloat16* outp = (seg == 0) ? Qb : (seg == 1) ? Kb : Vtb;

    for (int mt = 0; mt < 4; ++mt) {
        for (int nt = 0; nt < 4; ++nt) {
            int n = tileN + wc * 64 + nt * 16 + col;
            int nn = n & 511, h = nn >> 6, d = nn & 63;
            float bn = bias[nn];
            for (int r = 0; r < 4; ++r) {
                int m = tileM + wr * 64 + mt * 16 + quad * 4 + r;
                int b = m >> 12, s = m & 4095;
                float v = (acc[mt][nt][r] + bn) * scale;
                size_t off;
                if (seg < 2) off = (((size_t)(b * 8 + h) * 4096 + s) << 6) + d;
                else         off = (((size_t)(b * 8 + h) * 64 + d) << 12) + s;
                outp[off] = __float2bfloat16(v);
            }
        }
    }
}

// ---------------------------------------------------------------- final GEMM (Wo) (R6)
__global__ __launch_bounds__(256, 2) void gemm_out(
    const __hip_bfloat16* __restrict__ A, const __hip_bfloat16* __restrict__ Bt,
    const float* __restrict__ bias, float* __restrict__ out)
{
    const int N = 512, K = 512;
    __shared__ __hip_bfloat16 Abuf[128 * 32];
    __shared__ __hip_bfloat16 Bbuf[64 * 32];
    const int tid = threadIdx.x, w = tid >> 6, lane = tid & 63;
    const int col = lane & 15, quad = lane >> 4;
    const int tileN = blockIdx.x * 64, tileM = blockIdx.y * 128;

    f32x4 acc[2][4] = {};

    for (int k0 = 0; k0 < K; k0 += 32) {
        for (int i = 0; i < 2; ++i) {
            int g = w * 2 + i;
            int chunk = g * 64 + lane;
            int row = chunk >> 2, c8 = chunk & 3;
            gload16(A + (size_t)(tileM + row) * K + k0 + c8 * 8, Abuf + g * 512);
        }
        {
            int row = tid >> 2, c8 = tid & 3;
            gload16(Bt + (size_t)(tileN + row) * K + k0 + c8 * 8, Bbuf + tid * 8);
        }
        __syncthreads();
        bf16x8 af[2], bfr[4];
        for (int mt = 0; mt < 2; ++mt)
            af[mt] = *reinterpret_cast<const bf16x8*>(Abuf + (w * 32 + mt * 16 + col) * 32 + quad * 8);
        for (int nt = 0; nt < 4; ++nt)
            bfr[nt] = *reinterpret_cast<const bf16x8*>(Bbuf + (nt * 16 + col) * 32 + quad * 8);
        for (int mt = 0; mt < 2; ++mt)
            for (int nt = 0; nt < 4; ++nt)
                acc[mt][nt] = mfma16(af[mt], bfr[nt], acc[mt][nt]);
        __syncthreads();
    }

    for (int mt = 0; mt < 2; ++mt) {
        for (int nt = 0; nt < 4; ++nt) {
            int n = tileN + nt * 16 + col;
            float bn = bias[n];
            for (int r = 0; r < 4; ++r) {
                int m = tileM + w * 32 + mt * 16 + quad * 4 + r;
                out[(size_t)m * N + n] = acc[mt][nt][r] + bn;
            }
        }
    }
}

// ---------------------------------------------------------------- flash attention (v11)
// 2 waves x 64 q-rows (qg 0,1), 128 thr, split-KV (kvh halves), 32x32x16 MFMA,
// in-register softmax. Each K/V ds_read_b128 feeds 4 MFMAs. sc single-buffered;
// row-sums via VALU f32 adds + scalar permlane swap (no ones-MFMA).
__global__ __launch_bounds__(128, 2) void flash(
    const __hip_bfloat16* __restrict__ Q,   // [B*H, 4096, 64] (pre-scaled)
    const __hip_bfloat16* __restrict__ Kq,  // [B*H, 4096, 64]
    const __hip_bfloat16* __restrict__ Vt,  // [B*H, 64, 4096]
    __hip_bfloat16* __restrict__ O1,        // [B, 4096, 512] partial kvh=0
    __hip_bfloat16* __restrict__ O2,        // [B, 4096, 512] partial kvh=1
    float* __restrict__ Lb)                 // [2][16][4096] row-sums
{
    __shared__ __hip_bfloat16 KT[2][4096];  // 16 KB
    __shared__ __hip_bfloat16 VB[2][4096];  // 16 KB

    const int bh = blockIdx.y, b = bh >> 3, hq = bh & 7;
    const int kvh = blockIdx.z;
    const int base = kvh * 32;              // first kv tile for this block
    const int tid = threadIdx.x, w = tid >> 6, lane = tid & 63;
    const int l31 = lane & 31, hh = lane >> 5, l7 = lane & 7;
    const int q0 = blockIdx.x * 128 + w * 64;

    const __hip_bfloat16* Qh = Q + (size_t)bh * 4096 * 64;
    const __hip_bfloat16* Kh = Kq + (size_t)bh * 4096 * 64;
    const __hip_bfloat16* Vh = Vt + (size_t)bh * 64 * 4096;

    // Q fragments (B-operand): q = q0 + qg*32 + l31, d = dk*16 + hh*8 + j
    bf16x8 aq[2][4];
#pragma unroll
    for (int qg = 0; qg < 2; ++qg)
#pragma unroll
        for (int dk = 0; dk < 4; ++dk)
            aq[qg][dk] = *reinterpret_cast<const bf16x8*>(
                Qh + (size_t)(q0 + qg * 32 + l31) * 64 + dk * 16 + hh * 8);

    // K/V staging: 128 threads x 4 x 16B = one 64x64 bf16 tile per buffer.
    // Pre-swizzled global source (^ row&7), linear LDS dest. (v9-verified)
    const __hip_bfloat16* ksrc[4];
    const __hip_bfloat16* vsrc[4];
    int ldsoff[4];
#pragma unroll
    for (int i = 0; i < 4; ++i) {
        int c = i * 128 + tid;
        int row = c >> 3, s8 = (c & 7) ^ (row & 7);
        ksrc[i] = Kh + row * 64 + s8 * 8;
        vsrc[i] = Vh + (size_t)row * 4096 + s8 * 8;
        ldsoff[i] = (i * 128 + w * 64) * 8;
    }

    const f32x16 z16 = {};
    f32x16 o[2][2] = {};     // [qg][dg]; d = dg*32 + (reg&3)+8*(reg>>2)+4hh
    f32x16 sc[2][2];         // [qg][kg] (single-buffered)
    float ltot[2] = {0.f, 0.f};

    // prologue: K(base)->KT0, V(base)->VB0, K(base+1)->KT1
#pragma unroll
    for (int i = 0; i < 4; ++i) gload16(ksrc[i] + (size_t)base * 4096, &KT[0][ldsoff[i]]);
#pragma unroll
    for (int i = 0; i < 4; ++i) gload16(vsrc[i] + (size_t)base * 64, &VB[0][ldsoff[i]]);
#pragma unroll
    for (int i = 0; i < 4; ++i) gload16(ksrc[i] + (size_t)(base + 1) * 4096, &KT[1][ldsoff[i]]);
    __syncthreads();

#define QK_STEP(KR_)                                                            \
    _Pragma("unroll")                                                           \
    for (int kg = 0; kg < 2; ++kg) {                                            \
        _Pragma("unroll")                                                       \
        for (int dk = 0; dk < 4; ++dk) {                                        \
            bf16x8 ak = *reinterpret_cast<const bf16x8*>(                       \
                &KT[KR_][(kg * 32 + l31) * 64 + (((dk * 2 + hh) ^ l7) << 3)]);  \
            _Pragma("unroll")                                                   \
            for (int qg = 0; qg < 2; ++qg)                                      \
                sc[qg][kg] = (dk == 0) ? mfma32(ak, aq[qg][0], z16)             \
                                       : mfma32(ak, aq[qg][dk], sc[qg][kg]);    \
        }                                                                       \
    }

// Drains sc -> bp (frees sc for the next QK), accumulates row-sums into ltot.
#define SOFTMAX_BP()                                                            \
    bf16x8 bp[2][4];                                                            \
    _Pragma("unroll")                                                           \
    for (int qg = 0; qg < 2; ++qg) {                                            \
        float ls = 0.f;                                                         \
        uint32_t U[8][2];                                                       \
        _Pragma("unroll")                                                       \
        for (int kg = 0; kg < 2; ++kg) {                                        \
            f32x16 v = sc[qg][kg];                                              \
            _Pragma("unroll")                                                   \
            for (int rr = 0; rr < 4; ++rr) {                                    \
                float e0 = __builtin_amdgcn_exp2f(v[rr * 4 + 0]);               \
                float e1 = __builtin_amdgcn_exp2f(v[rr * 4 + 1]);               \
                float e2 = __builtin_amdgcn_exp2f(v[rr * 4 + 2]);               \
                float e3 = __builtin_amdgcn_exp2f(v[rr * 4 + 3]);               \
                ls += (e0 + e1) + (e2 + e3);                                    \
                U[kg * 4 + rr][0] = pkbf(e0, e1);                               \
                U[kg * 4 + rr][1] = pkbf(e2, e3);                               \
            }                                                                   \
        }                                                                       \
        union fu_ { float f; uint32_t u; };                                     \
        fu_ la, lb2;                                                            \
        la.f = ls; lb2.u = la.u;                                                \
        pl32swap(la.u, lb2.u);                                                  \
        ltot[qg] += la.f + lb2.f;                                               \
        _Pragma("unroll")                                                       \
        for (int kb = 0; kb < 4; ++kb) {                                        \
            pl32swap(U[2 * kb][0], U[2 * kb + 1][0]);                           \
            pl32swap(U[2 * kb][1], U[2 * kb + 1][1]);                           \
            union { uint32_t u[4]; bf16x8 v8; } cc;                             \
            cc.u[0] = U[2 * kb][0];     cc.u[1] = U[2 * kb][1];                 \
            cc.u[2] = U[2 * kb + 1][0]; cc.u[3] = U[2 * kb + 1][1];             \
            bp[qg][kb] = cc.v8;                                                 \
        }                                                                       \
    }

#define PV_STEP(VR_)                                                            \
    _Pragma("unroll")                                                           \
    for (int dg = 0; dg < 2; ++dg) {                                            \
        _Pragma("unroll")                                                       \
        for (int kb = 0; kb < 4; ++kb) {                                        \
            bf16x8 av = *reinterpret_cast<const bf16x8*>(                       \
                &VB[VR_][(dg * 32 + l31) * 64 + (((kb * 2 + hh) ^ l7) << 3)]);  \
            _Pragma("unroll")                                                   \
            for (int qg = 0; qg < 2; ++qg)                                      \
                o[qg][dg] = mfma32(av, bp[qg][kb], o[qg][dg]);                  \
        }                                                                       \
    }

    // prologue scores for tile base (from KT[0])
    QK_STEP(0)
    __syncthreads();

#define FLASH_BODY(T_, P_)                                                      \
    {                                                                           \
        const int kt_ = (T_);                                                   \
        int kk = kt_ + 2; if (kk > base + 31) kk = base + 31;                   \
        _Pragma("unroll")                                                       \
        for (int i = 0; i < 4; ++i)                                             \
            gload16(ksrc[i] + (size_t)kk * 4096, &KT[(P_)][ldsoff[i]]);         \
        _Pragma("unroll")                                                       \
        for (int i = 0; i < 4; ++i)                                             \
            gload16(vsrc[i] + (size_t)(kt_ + 1) * 64, &VB[1 - (P_)][ldsoff[i]]);\
        SOFTMAX_BP()                                                            \
        QK_STEP(1 - (P_))                                                       \
        PV_STEP(P_)                                                             \
        __syncthreads();                                                        \
    }

    // bodies: tiles base+0 .. base+30 (31 bodies), tail = base+31
    FLASH_BODY(base + 0, 0)
    for (int kth = 0; kth < 15; ++kth) {
        FLASH_BODY(base + 2 * kth + 1, 1)
        FLASH_BODY(base + 2 * kth + 2, 0)
    }
    // tail: tile base+31 — softmax on sc, PV from VB[1]
    {
        SOFTMAX_BP()
        PV_STEP(1)
    }
#undef FLASH_BODY
#undef PV_STEP
#undef SOFTMAX_BP
#undef QK_STEP

#pragma unroll
    for (int qg = 0; qg < 2; ++qg) {
        float l = ltot[qg];
        float inv = 1.0f / l;
        int s = q0 + qg * 32 + l31;
        __hip_bfloat16* Od = kvh ? O2 : O1;
        __hip_bfloat16* dst = Od + ((size_t)b * 4096 + s) * 512 + hq * 64;
#pragma unroll
        for (int dg = 0; dg < 2; ++dg)
#pragma unroll
            for (int rr = 0; rr < 4; ++rr) {
                uint2 u;
                u.x = pkbf(o[qg][dg][rr * 4 + 0] * inv, o[qg][dg][rr * 4 + 1] * inv);
                u.y = pkbf(o[qg][dg][rr * 4 + 2] * inv, o[qg][dg][rr * 4 + 3] * inv);
                *reinterpret_cast<uint2*>(dst + dg * 32 + rr * 8 + hh * 4) = u;
            }
        if (hh == 0)
            Lb[((size_t)kvh * 16 + bh) * 4096 + s] = l;
    }
}

// ---------------------------------------------------------------- partial merge
// O = (l1*O1^ + l2*O2^)/(l1+l2), 8 bf16 per thread.
__global__ __launch_bounds__(256) void merge_po(
    const __hip_bfloat16* __restrict__ O1, const __hip_bfloat16* __restrict__ O2,
    const float* __restrict__ Lb, __hip_bfloat16* __restrict__ Am)
{
    int c = blockIdx.x * 256 + threadIdx.x;   // chunk of 8 elems
    int flat = c * 8;                         // [b][s][d512]
    int d = flat & 511, s = (flat >> 9) & 4095, b = flat >> 21;
    int bh = b * 8 + (d >> 6);
    float l1 = Lb[(size_t)bh * 4096 + s];
    float l2 = Lb[(size_t)(16 + bh) * 4096 + s];
    float rs = 1.0f / (l1 + l2);
    float w1 = l1 * rs, w2 = l2 * rs;
    bf16x8 a = *reinterpret_cast<const bf16x8*>(O1 + flat);
    bf16x8 bb = *reinterpret_cast<const bf16x8*>(O2 + flat);
    float r0 = w1 * (float)a[0] + w2 * (float)bb[0];
    float r1 = w1 * (float)a[1] + w2 * (float)bb[1];
    float r2 = w1 * (float)a[2] + w2 * (float)bb[2];
    float r3 = w1 * (float)a[3] + w2 * (float)bb[3];
    float r4 = w1 * (float)a[4] + w2 * (float)bb[4];
    float r5 = w1 * (float)a[5] + w2 * (float)bb[5];
    float r6 = w1 * (float)a[6] + w2 * (float)bb[6];
    float r7 = w1 * (float)a[7] + w2 * (float)bb[7];
    uint4 uu;
    uu.x = pkbf(r0, r1);
    uu.y = pkbf(r2, r3);
    uu.z = pkbf(r4, r5);
    uu.w = pkbf(r6, r7);
    *reinterpret_cast<uint4*>(Am + flat) = uu;
}

// ---------------------------------------------------------------- launch
extern "C" void kernel_launch(void* const* d_in, const int* in_sizes, int n_in,
                              void* d_out, int out_size, void* d_ws, size_t ws_size,
                              hipStream_t stream) {
    const float* X  = (const float*)d_in[0];
    const float* Wq = (const float*)d_in[1];
    const float* bq = (const float*)d_in[2];
    const float* Wk = (const float*)d_in[3];
    const float* bk = (const float*)d_in[4];
    const float* Wv = (const float*)d_in[5];
    const float* bv = (const float*)d_in[6];
    const float* Wo = (const float*)d_in[7];
    const float* bo = (const float*)d_in[8];
    float* out = (float*)d_out;

    char* ws = (char*)d_ws;
    __hip_bfloat16* Xb  = (__hip_bfloat16*)(ws);
    __hip_bfloat16* Wqt = (__hip_bfloat16*)(ws + ((size_t)8 << 20));
    __hip_bfloat16* Wkt = Wqt + 512 * 512;
    __hip_bfloat16* Wvt = Wkt + 512 * 512;
    __hip_bfloat16* Wot = Wvt + 512 * 512;
    __hip_bfloat16* Qb  = (__hip_bfloat16*)(ws + ((size_t)10 << 20));
    __hip_bfloat16* Kb  = (__hip_bfloat16*)(ws + ((size_t)18 << 20));
    __hip_bfloat16* Vtb = (__hip_bfloat16*)(ws + ((size_t)26 << 20));
    __hip_bfloat16* O1  = (__hip_bfloat16*)(ws + ((size_t)34 << 20));
    __hip_bfloat16* O2  = (__hip_bfloat16*)(ws);                    // reuse Xb
    __hip_bfloat16* Am  = (__hip_bfloat16*)(ws + ((size_t)10 << 20)); // reuse Qb
    float* Lb = (float*)d_out;                                      // scratch head of out

    cvt_all<<<5120, 256, 0, stream>>>(X, Xb, Wq, Wk, Wv, Wo, Wqt, Wkt, Wvt, Wot);

    const float qs = 0.125f * 1.4426950408889634f;  // (1/sqrt(64)) * log2(e)
    gemm_qkv<<<dim3(12, 64), 256, 0, stream>>>(Xb, Wqt, bq, bk, bv, Qb, Kb, Vtb, qs);
    flash<<<dim3(32, 16, 2), 128, 0, stream>>>(Qb, Kb, Vtb, O1, O2, Lb);
    merge_po<<<2048, 256, 0, stream>>>(O1, O2, Lb, Am);
    gemm_out<<<dim3(8, 64), 256, 0, stream>>>(Am, Wot, bo, out);
}

// Round 10
// 215.897 us; speedup vs baseline: 1.0312x; 1.0312x over previous
//
#include <hip/hip_runtime.h>
#include <hip/hip_bf16.h>
#include <stdint.h>

// Problem: B=2, S=4096, D=512, H=8, hd=64. fp32 in/out, bf16 MFMA internally.
// Dispatches: cvt_all -> gemm_qkv -> flash -> gemm_out.
// R17 (v12): back to the v8b pipeline (no split-KV/merge). Flash restructured
// to 2-kv-tiles-per-barrier windows: KT/VB double buffers hold 2 tiles (64KB
// LDS), per window {8 gloads next -> QK(t0) -> QK(t1) -> SM(sc0)/PV(t0) ->
// SM(sc1)/PV(t1) -> 1 barrier}. Halves the per-body __syncthreads drain count
// (R9 audit: ~1250 cyc dual-wave stall per barrier) while QK(t1) MFMAs overlap
// SM(sc0) VALU and PV(t0) overlaps SM(sc1). Row-sum stays on MFMA pipe
// (ones-MFMA; R9 lesson: VALU is the leading pipe). Non-flash unchanged (R6).
//
// ws layout:
//   [0,   8MB)  Xb    bf16 [8192,512]
//   [8,  10MB)  Wqt/Wkt/Wvt/Wot bf16 [512,512] each ([n][k]; QKV contiguous)
//   [10, 18MB)  Qb    bf16 [B,H,S,64]  (pre-scaled by 0.125*log2e)
//   [18, 26MB)  Kb    bf16 [B,H,S,64]
//   [26, 34MB)  Vtb   bf16 [B,H,64,S]
//   [34, 42MB)  Atb   bf16 [B,S,512]

typedef __bf16 bf16x8 __attribute__((ext_vector_type(8)));
typedef float f32x4 __attribute__((ext_vector_type(4)));
typedef float f32x16 __attribute__((ext_vector_type(16)));

using as1_void = __attribute__((address_space(1))) void;
using as3_void = __attribute__((address_space(3))) void;

__device__ __forceinline__ void gload16(const void* g, void* l) {
    __builtin_amdgcn_global_load_lds((const as1_void*)g, (as3_void*)l, 16, 0, 0);
}

__device__ __forceinline__ f32x4 mfma16(bf16x8 a, bf16x8 b, f32x4 c) {
    return __builtin_amdgcn_mfma_f32_16x16x32_bf16(a, b, c, 0, 0, 0);
}

__device__ __forceinline__ f32x16 mfma32(bf16x8 a, bf16x8 b, f32x16 c) {
    return __builtin_amdgcn_mfma_f32_32x32x16_bf16(a, b, c, 0, 0, 0);
}

__device__ __forceinline__ uint32_t pkbf(float a, float b) {
    union { __hip_bfloat16 h[2]; uint32_t u; } r;
    r.h[0] = __float2bfloat16(a);   // low 16 = even element
    r.h[1] = __float2bfloat16(b);
    return r.u;
}

// Exchange: a's hi-32-lane values <-> b's lo-32-lane values.
__device__ __forceinline__ void pl32swap(uint32_t& a, uint32_t& b) {
#if __has_builtin(__builtin_amdgcn_permlane32_swap)
    typedef unsigned int uint32x2_t __attribute__((ext_vector_type(2)));
    uint32x2_t r = __builtin_amdgcn_permlane32_swap(a, b, false, false);
    a = r[0];
    b = r[1];
#else
    asm volatile("v_permlane32_swap_b32 %0, %1" : "+v"(a), "+v"(b));
#endif
}

// ---------------------------------------------------------------- converts (fused)
__global__ void cvt_all(const float* __restrict__ X, __hip_bfloat16* __restrict__ Xb,
                        const float* __restrict__ w0, const float* __restrict__ w1,
                        const float* __restrict__ w2, const float* __restrict__ w3,
                        __hip_bfloat16* __restrict__ o0, __hip_bfloat16* __restrict__ o1,
                        __hip_bfloat16* __restrict__ o2, __hip_bfloat16* __restrict__ o3) {
    __shared__ float t[32][33];
    const int bid = blockIdx.x, tid = threadIdx.x;
    if (bid < 1024) {
        const float* W; __hip_bfloat16* O;
        switch (bid >> 8) {
            case 0: W = w0; O = o0; break;
            case 1: W = w1; O = o1; break;
            case 2: W = w2; O = o2; break;
            default: W = w3; O = o3; break;
        }
        int rem = bid & 255;
        int n0 = (rem & 15) * 32, k0 = (rem >> 4) * 32;
        int tx = tid & 31, ty = tid >> 5;
        for (int j = 0; j < 4; ++j)
            t[ty + 8 * j][tx] = W[(size_t)(k0 + ty + 8 * j) * 512 + n0 + tx];
        __syncthreads();
        for (int j = 0; j < 4; ++j)
            O[(size_t)(n0 + ty + 8 * j) * 512 + k0 + tx] = __float2bfloat16(t[tx][ty + 8 * j]);
    } else {
        int i = ((bid - 1024) * 256 + tid) * 4;   // covers exactly 8192*512
        float4 v = *reinterpret_cast<const float4*>(X + i);
        uint2 u;
        u.x = pkbf(v.x, v.y);
        u.y = pkbf(v.z, v.w);
        *reinterpret_cast<uint2*>(Xb + i) = u;
    }
}

// ---------------------------------------------------------------- fused QKV GEMM (R6)
__global__ __launch_bounds__(256, 2) void gemm_qkv(
    const __hip_bfloat16* __restrict__ A, const __hip_bfloat16* __restrict__ Bt,
    const float* __restrict__ bq, const float* __restrict__ bk, const float* __restrict__ bv,
    __hip_bfloat16* __restrict__ Qb, __hip_bfloat16* __restrict__ Kb,
    __hip_bfloat16* __restrict__ Vtb, float qs)
{
    const int K = 512;
    __shared__ __hip_bfloat16 Abuf[128 * 32];
    __shared__ __hip_bfloat16 Bbuf[128 * 32];
    const int tid = threadIdx.x, w = tid >> 6, lane = tid & 63;
    const int col = lane & 15, quad = lane >> 4;
    const int wr = w >> 1, wc = w & 1;
    const int tileN = blockIdx.x * 128, tileM = blockIdx.y * 128;

    f32x4 acc[4][4] = {};

    for (int k0 = 0; k0 < K; k0 += 32) {
        for (int i = 0; i < 2; ++i) {
            int g = w * 2 + i;
            int chunk = g * 64 + lane;
            int row = chunk >> 2, c8 = chunk & 3;
            gload16(A + (size_t)(tileM + row) * K + k0 + c8 * 8, Abuf + g * 512);
            gload16(Bt + (size_t)(tileN + row) * K + k0 + c8 * 8, Bbuf + g * 512);
        }
        __syncthreads();
        bf16x8 af[4], bfr[4];
        for (int mt = 0; mt < 4; ++mt)
            af[mt] = *reinterpret_cast<const bf16x8*>(Abuf + (wr * 64 + mt * 16 + col) * 32 + quad * 8);
        for (int nt = 0; nt < 4; ++nt)
            bfr[nt] = *reinterpret_cast<const bf16x8*>(Bbuf + (wc * 64 + nt * 16 + col) * 32 + quad * 8);
        for (int mt = 0; mt < 4; ++mt)
            for (int nt = 0; nt < 4; ++nt)
                acc[mt][nt] = mfma16(af[mt], bfr[nt], acc[mt][nt]);
        __syncthreads();
    }

    const int seg = (tileN + wc * 64) >> 9;   // wave-uniform
    const float* bias = (seg == 0) ? bq : (seg == 1) ? bk : bv;
    const float scale = (seg == 0) ? qs : 1.0f;
    __hip_bfloat16* outp = (seg == 0) ? Qb : (seg == 1) ? Kb : Vtb;

    for (int mt = 0; mt < 4; ++mt) {
        for (int nt = 0; nt < 4; ++nt) {
            int n = tileN + wc * 64 + nt * 16 + col;
            int nn = n & 511, h = nn >> 6, d = nn & 63;
            float bn = bias[nn];
            for (int r = 0; r < 4; ++r) {
                int m = tileM + wr * 64 + mt * 16 + quad * 4 + r;
                int b = m >> 12, s = m & 4095;
                float v = (acc[mt][nt][r] + bn) * scale;
                size_t off;
                if (seg < 2) off = (((size_t)(b * 8 + h) * 4096 + s) << 6) + d;
                else         off = (((size_t)(b * 8 + h) * 64 + d) << 12) + s;
                outp[off] = __float2bfloat16(v);
            }
        }
    }
}

// ---------------------------------------------------------------- final GEMM (Wo) (R6)
__global__ __launch_bounds__(256, 2) void gemm_out(
    const __hip_bfloat16* __restrict__ A, const __hip_bfloat16* __restrict__ Bt,
    const float* __restrict__ bias, float* __restrict__ out)
{
    const int N = 512, K = 512;
    __shared__ __hip_bfloat16 Abuf[128 * 32];
    __shared__ __hip_bfloat16 Bbuf[64 * 32];
    const int tid = threadIdx.x, w = tid >> 6, lane = tid & 63;
    const int col = lane & 15, quad = lane >> 4;
    const int tileN = blockIdx.x * 64, tileM = blockIdx.y * 128;

    f32x4 acc[2][4] = {};

    for (int k0 = 0; k0 < K; k0 += 32) {
        for (int i = 0; i < 2; ++i) {
            int g = w * 2 + i;
            int chunk = g * 64 + lane;
            int row = chunk >> 2, c8 = chunk & 3;
            gload16(A + (size_t)(tileM + row) * K + k0 + c8 * 8, Abuf + g * 512);
        }
        {
            int row = tid >> 2, c8 = tid & 3;
            gload16(Bt + (size_t)(tileN + row) * K + k0 + c8 * 8, Bbuf + tid * 8);
        }
        __syncthreads();
        bf16x8 af[2], bfr[4];
        for (int mt = 0; mt < 2; ++mt)
            af[mt] = *reinterpret_cast<const bf16x8*>(Abuf + (w * 32 + mt * 16 + col) * 32 + quad * 8);
        for (int nt = 0; nt < 4; ++nt)
            bfr[nt] = *reinterpret_cast<const bf16x8*>(Bbuf + (nt * 16 + col) * 32 + quad * 8);
        for (int mt = 0; mt < 2; ++mt)
            for (int nt = 0; nt < 4; ++nt)
                acc[mt][nt] = mfma16(af[mt], bfr[nt], acc[mt][nt]);
        __syncthreads();
    }

    for (int mt = 0; mt < 2; ++mt) {
        for (int nt = 0; nt < 4; ++nt) {
            int n = tileN + nt * 16 + col;
            float bn = bias[n];
            for (int r = 0; r < 4; ++r) {
                int m = tileM + w * 32 + mt * 16 + quad * 4 + r;
                out[(size_t)m * N + n] = acc[mt][nt][r] + bn;
            }
        }
    }
}

// ---------------------------------------------------------------- flash attention (v12)
// v8b math (4 waves x 32 q-rows, 32x32x16 MFMA, in-register softmax), 2-tile
// windows: one __syncthreads per 2 kv-tiles. LDS 64KB: KT[2][8192]+VB[2][8192].
__global__ __launch_bounds__(256, 2) void flash(
    const __hip_bfloat16* __restrict__ Q,   // [B*H, 4096, 64] (pre-scaled)
    const __hip_bfloat16* __restrict__ Kq,  // [B*H, 4096, 64]
    const __hip_bfloat16* __restrict__ Vt,  // [B*H, 64, 4096]
    __hip_bfloat16* __restrict__ attnb)     // [B, 4096, 512]
{
    __shared__ __hip_bfloat16 KT[2][8192];  // 32 KB: [buf][tile(2)*4096 + ...]
    __shared__ __hip_bfloat16 VB[2][8192];  // 32 KB

    const int bh = blockIdx.y, b = bh >> 3, hq = bh & 7;
    const int tid = threadIdx.x, w = tid >> 6, lane = tid & 63;
    const int l31 = lane & 31, hh = lane >> 5, l7 = lane & 7;
    const int q0 = blockIdx.x * 128 + w * 32;

    const __hip_bfloat16* Qh = Q + (size_t)bh * 4096 * 64;
    const __hip_bfloat16* Kh = Kq + (size_t)bh * 4096 * 64;
    const __hip_bfloat16* Vh = Vt + (size_t)bh * 64 * 4096;

    // Q fragments (B-operand): lane q = l31, d = dk*16 + hh*8 + j
    bf16x8 aq[4];
#pragma unroll
    for (int dk = 0; dk < 4; ++dk)
        aq[dk] = *reinterpret_cast<const bf16x8*>(
            Qh + (size_t)(q0 + l31) * 64 + dk * 16 + hh * 8);

    // K/V staging: pre-swizzled global source (^ row&7), linear LDS dest.
    const __hip_bfloat16* ksrc[2];
    const __hip_bfloat16* vsrc[2];
    int ldsoff[2];
#pragma unroll
    for (int i = 0; i < 2; ++i) {
        int c = i * 256 + tid;
        int row = c >> 3, s8 = (c & 7) ^ (row & 7);
        ksrc[i] = Kh + row * 64 + s8 * 8;
        vsrc[i] = Vh + (size_t)row * 4096 + s8 * 8;
        ldsoff[i] = (i * 256 + w * 64) * 8;
    }

    bf16x8 ones;
#pragma unroll
    for (int j = 0; j < 8; ++j) ones[j] = (__bf16)1.0f;

    const f32x16 z16 = {};
    f32x16 o[2] = {};        // D[d][q]: d = dg*32 + (reg&3)+8*(reg>>2)+4hh
    f32x16 lacc = {};        // row-sums via ones-MFMA (MFMA pipe — R9 lesson)
    f32x16 sc0[2], sc1[2];   // scores for the window's two tiles

    // prologue: stage window 0 (tiles 0,1)
#pragma unroll
    for (int t2 = 0; t2 < 2; ++t2)
#pragma unroll
        for (int i = 0; i < 2; ++i) {
            gload16(ksrc[i] + (size_t)t2 * 4096, &KT[0][t2 * 4096 + ldsoff[i]]);
            gload16(vsrc[i] + (size_t)t2 * 64,  &VB[0][t2 * 4096 + ldsoff[i]]);
        }
    __syncthreads();

#define QK_T(P_, T2_, SC_)                                                      \
    _Pragma("unroll")                                                           \
    for (int kg = 0; kg < 2; ++kg) {                                            \
        _Pragma("unroll")                                                       \
        for (int dk = 0; dk < 4; ++dk) {                                        \
            bf16x8 ak = *reinterpret_cast<const bf16x8*>(                       \
                &KT[P_][(T2_) * 4096 + (kg * 32 + l31) * 64 +                   \
                        (((dk * 2 + hh) ^ l7) << 3)]);                          \
            SC_[kg] = (dk == 0) ? mfma32(ak, aq[0], z16)                        \
                                : mfma32(ak, aq[dk], SC_[kg]);                  \
        }                                                                       \
    }

#define SM_T(SC_, BP_)                                                          \
    {                                                                           \
        uint32_t U[8][2];                                                       \
        _Pragma("unroll")                                                       \
        for (int kg = 0; kg < 2; ++kg) {                                        \
            f32x16 v = SC_[kg];                                                 \
            _Pragma("unroll")                                                   \
            for (int rr = 0; rr < 4; ++rr) {                                    \
                U[kg * 4 + rr][0] = pkbf(__builtin_amdgcn_exp2f(v[rr * 4 + 0]), \
                                         __builtin_amdgcn_exp2f(v[rr * 4 + 1]));\
                U[kg * 4 + rr][1] = pkbf(__builtin_amdgcn_exp2f(v[rr * 4 + 2]), \
                                         __builtin_amdgcn_exp2f(v[rr * 4 + 3]));\
            }                                                                   \
        }                                                                       \
        _Pragma("unroll")                                                       \
        for (int kb = 0; kb < 4; ++kb) {                                        \
            pl32swap(U[2 * kb][0], U[2 * kb + 1][0]);                           \
            pl32swap(U[2 * kb][1], U[2 * kb + 1][1]);                           \
            union { uint32_t u[4]; bf16x8 v8; } cc;                             \
            cc.u[0] = U[2 * kb][0];     cc.u[1] = U[2 * kb][1];                 \
            cc.u[2] = U[2 * kb + 1][0]; cc.u[3] = U[2 * kb + 1][1];             \
            BP_[kb] = cc.v8;                                                    \
        }                                                                       \
    }

#define PV_T(P_, T2_, BP_)                                                      \
    _Pragma("unroll")                                                           \
    for (int dg = 0; dg < 2; ++dg) {                                            \
        _Pragma("unroll")                                                       \
        for (int kb = 0; kb < 4; ++kb) {                                        \
            bf16x8 av = *reinterpret_cast<const bf16x8*>(                       \
                &VB[P_][(T2_) * 4096 + (dg * 32 + l31) * 64 +                   \
                        (((kb * 2 + hh) ^ l7) << 3)]);                          \
            o[dg] = mfma32(av, BP_[kb], o[dg]);                                 \
        }                                                                       \
    }                                                                           \
    _Pragma("unroll")                                                           \
    for (int kb = 0; kb < 4; ++kb) lacc = mfma32(ones, BP_[kb], lacc);

// Window W_ (parity P_): tiles {2W, 2W+1} resident in KT/VB[P_].
// Stage next window's 2 K-tiles + 2 V-tiles into buf 1-P_ (clamped at end).
#define WINDOW(W_, P_)                                                          \
    {                                                                           \
        const int t0_ = 2 * (W_);                                               \
        int ka = t0_ + 2; if (ka > 62) ka = 62;                                 \
        int kb2 = t0_ + 3; if (kb2 > 63) kb2 = 63;                              \
        gload16(ksrc[0] + (size_t)ka * 4096, &KT[1 - (P_)][ldsoff[0]]);         \
        gload16(ksrc[1] + (size_t)ka * 4096, &KT[1 - (P_)][ldsoff[1]]);         \
        gload16(ksrc[0] + (size_t)kb2 * 4096, &KT[1 - (P_)][4096 + ldsoff[0]]); \
        gload16(ksrc[1] + (size_t)kb2 * 4096, &KT[1 - (P_)][4096 + ldsoff[1]]); \
        gload16(vsrc[0] + (size_t)ka * 64, &VB[1 - (P_)][ldsoff[0]]);           \
        gload16(vsrc[1] + (size_t)ka * 64, &VB[1 - (P_)][ldsoff[1]]);           \
        gload16(vsrc[0] + (size_t)kb2 * 64, &VB[1 - (P_)][4096 + ldsoff[0]]);   \
        gload16(vsrc[1] + (size_t)kb2 * 64, &VB[1 - (P_)][4096 + ldsoff[1]]);   \
        QK_T(P_, 0, sc0)                                                        \
        QK_T(P_, 1, sc1)                                                        \
        {                                                                       \
            bf16x8 bpA[4];                                                      \
            SM_T(sc0, bpA)                                                      \
            PV_T(P_, 0, bpA)                                                    \
        }                                                                       \
        {                                                                       \
            bf16x8 bpB[4];                                                      \
            SM_T(sc1, bpB)                                                      \
            PV_T(P_, 1, bpB)                                                    \
        }                                                                       \
        __syncthreads();                                                        \
    }

    for (int wh = 0; wh < 16; ++wh) {
        WINDOW(2 * wh, 0)
        WINDOW(2 * wh + 1, 1)
    }
#undef WINDOW
#undef PV_T
#undef SM_T
#undef QK_T

    {
        float inv = 1.0f / lacc[0];
        int s = q0 + l31;
        __hip_bfloat16* dst = attnb + ((size_t)b * 4096 + s) * 512 + hq * 64;
#pragma unroll
        for (int dg = 0; dg < 2; ++dg)
#pragma unroll
            for (int rr = 0; rr < 4; ++rr) {
                uint2 u;
                u.x = pkbf(o[dg][rr * 4 + 0] * inv, o[dg][rr * 4 + 1] * inv);
                u.y = pkbf(o[dg][rr * 4 + 2] * inv, o[dg][rr * 4 + 3] * inv);
                *reinterpret_cast<uint2*>(dst + dg * 32 + rr * 8 + hh * 4) = u;
            }
    }
}

// ---------------------------------------------------------------- launch
extern "C" void kernel_launch(void* const* d_in, const int* in_sizes, int n_in,
                              void* d_out, int out_size, void* d_ws, size_t ws_size,
                              hipStream_t stream) {
    const float* X  = (const float*)d_in[0];
    const float* Wq = (const float*)d_in[1];
    const float* bq = (const float*)d_in[2];
    const float* Wk = (const float*)d_in[3];
    const float* bk = (const float*)d_in[4];
    const float* Wv = (const float*)d_in[5];
    const float* bv = (const float*)d_in[6];
    const float* Wo = (const float*)d_in[7];
    const float* bo = (const float*)d_in[8];
    float* out = (float*)d_out;

    char* ws = (char*)d_ws;
    __hip_bfloat16* Xb  = (__hip_bfloat16*)(ws);
    __hip_bfloat16* Wqt = (__hip_bfloat16*)(ws + ((size_t)8 << 20));
    __hip_bfloat16* Wkt = Wqt + 512 * 512;
    __hip_bfloat16* Wvt = Wkt + 512 * 512;
    __hip_bfloat16* Wot = Wvt + 512 * 512;
    __hip_bfloat16* Qb  = (__hip_bfloat16*)(ws + ((size_t)10 << 20));
    __hip_bfloat16* Kb  = (__hip_bfloat16*)(ws + ((size_t)18 << 20));
    __hip_bfloat16* Vtb = (__hip_bfloat16*)(ws + ((size_t)26 << 20));
    __hip_bfloat16* Atb = (__hip_bfloat16*)(ws + ((size_t)34 << 20));

    cvt_all<<<5120, 256, 0, stream>>>(X, Xb, Wq, Wk, Wv, Wo, Wqt, Wkt, Wvt, Wot);

    const float qs = 0.125f * 1.4426950408889634f;  // (1/sqrt(64)) * log2(e)
    gemm_qkv<<<dim3(12, 64), 256, 0, stream>>>(Xb, Wqt, bq, bk, bv, Qb, Kb, Vtb, qs);
    flash<<<dim3(32, 16), 256, 0, stream>>>(Qb, Kb, Vtb, Atb);
    gemm_out<<<dim3(8, 64), 256, 0, stream>>>(Atb, Wot, bo, out);
}